// Round 21
// baseline (61.673 us; speedup 1.0000x reference)
//
#include <hip/hip_runtime.h>

#define KS    13
#define HALF  6
#define TY    32              // output rows per strip (R13 geometry — best measured)
#define NITER (TY + 12)       // 44 staged rows
#define NK    (NITER / 2)     // 22 iterations, 2 rows per barrier
#define SW    1040            // padded row: 8 halo + 1024 + 8 halo
#define IMG_H 1024
#define IMG_W 1024

__device__ __forceinline__ int reflect_idx(int i, int n) {
    if (i < 0) i = -i;
    if (i >= n) i = 2 * n - 2 - i;
    return i;
}

struct Ctx {
    const float* xin;
    float*       o;
    float        g[KS];
    int          t;        // thread's column granule: cols 4t..4t+3
    int          r0;       // strip's first output row
    bool         hasHalo;  // tid < 16: also stages one halo float per row
    int          hcol;     // reflected image col for this thread's halo float
    int          hoff;     // padded-row offset of this thread's halo float
};

// H-filter one staged PADDED row from LDS: 5 aligned b128 reads, 13 taps x 4
// cols. BRANCH-FREE for all threads (halo pre-staged) -- the old interior/edge
// branch made waves 0 and 3 execute 20 extra ds_read_b32 per call (exec-masked
// divergence), and those straggler waves set every barrier's critical path.
__device__ __forceinline__ float4 h_filter(const float* srow, const Ctx& cx) {
    float f[20];
    #pragma unroll
    for (int k = 0; k < 5; ++k) {
        float4 v = *reinterpret_cast<const float4*>(srow + 4 * cx.t + 4 * k);
        f[4*k+0] = v.x; f[4*k+1] = v.y; f[4*k+2] = v.z; f[4*k+3] = v.w;
    }
    // f[m] = padded[4t+m] = raw col 4t+m-8; out col 4t+u taps raw 4t+u-6..+6
    float4 h = make_float4(0.f, 0.f, 0.f, 0.f);
    #pragma unroll
    for (int j = 0; j < KS; ++j) {
        h.x += cx.g[j] * f[2 + j];
        h.y += cx.g[j] * f[3 + j];
        h.z += cx.g[j] * f[4 + j];
        h.w += cx.g[j] * f[5 + j];
    }
    return h;
}

// Iteration k (= outer*7 + U): commit staged rows 2k,2k+1 (main granule + halo
// float) to the (k&1) LDS pair, prefetch rows 2k+2,2k+3 into registers (in
// flight across barrier+compute), ONE barrier, H-filter both rows into window
// slots (2U)%14,(2U+1)%14, V-filter -> output rows r0+2k-12, r0+2k-11.
// Window indices compile-time (rule #20). WAR safety: iter k's reads precede
// barrier_{k+1}; iter k+2's rewrites of this pair follow it (R13 proof).
template<int U>
__device__ __forceinline__ void body2(int outer, const Ctx& cx, float (*s)[SW],
                                      float4 (&w)[14], float4& cur0, float4& cur1,
                                      float& hal0, float& hal1)
{
    const int k = outer * 7 + U;
    if (k >= NK) return;                 // block-uniform guard (barrier-safe)
    const int n0 = 2 * k;
    const int bp = (k & 1) * 2;          // LDS buffer pair

    // commit staged rows (main granules 16B-aligned at 32+16t; halo scalar)
    *reinterpret_cast<float4*>(&s[bp + 0][8 + 4 * cx.t]) = cur0;
    *reinterpret_cast<float4*>(&s[bp + 1][8 + 4 * cx.t]) = cur1;
    if (cx.hasHalo) {
        s[bp + 0][cx.hoff] = hal0;
        s[bp + 1][cx.hoff] = hal1;
    }
    // prefetch next pair: rows n0+2,n0+3 = input rows r0+n0-4, r0+n0-3 (T14)
    if (k + 1 < NK) {
        const float* ra = cx.xin + (size_t)reflect_idx(cx.r0 + n0 - 4, IMG_H) * IMG_W;
        const float* rb = cx.xin + (size_t)reflect_idx(cx.r0 + n0 - 3, IMG_H) * IMG_W;
        cur0 = *reinterpret_cast<const float4*>(ra + 4 * cx.t);
        cur1 = *reinterpret_cast<const float4*>(rb + 4 * cx.t);
        if (cx.hasHalo) {
            hal0 = ra[cx.hcol];
            hal1 = rb[cx.hcol];
        }
    }
    __syncthreads();

    // two H-filters into the rolling 14-slot window
    w[(2 * U) % 14]     = h_filter(s[bp + 0], cx);
    w[(2 * U + 1) % 14] = h_filter(s[bp + 1], cx);

    // two V-filters -> output rows r0+n0-12, r0+n0-11
    if (n0 >= 12) {
        float4 a0 = make_float4(0.f, 0.f, 0.f, 0.f);
        float4 a1 = make_float4(0.f, 0.f, 0.f, 0.f);
        #pragma unroll
        for (int j = 0; j < KS; ++j) {
            const float4 v0 = w[(2 * U + 2 + j) % 14];
            const float4 v1 = w[(2 * U + 3 + j) % 14];
            a0.x += cx.g[j] * v0.x;  a1.x += cx.g[j] * v1.x;
            a0.y += cx.g[j] * v0.y;  a1.y += cx.g[j] * v1.y;
            a0.z += cx.g[j] * v0.z;  a1.z += cx.g[j] * v1.z;
            a0.w += cx.g[j] * v0.w;  a1.w += cx.g[j] * v1.w;
        }
        *reinterpret_cast<float4*>(cx.o + (size_t)(cx.r0 + n0 - 12) * IMG_W + 4 * cx.t) = a0;
        *reinterpret_cast<float4*>(cx.o + (size_t)(cx.r0 + n0 - 11) * IMG_W + 4 * cx.t) = a1;
    }
}

// No launch-bounds min-waves (R2: VGPR cap -> spill). Expect ~105 VGPR.
__global__ __launch_bounds__(256) void gauss_blur_stream(
    const float* __restrict__ x, const float* __restrict__ k2d,
    float* __restrict__ out)
{
    __shared__ float s[4][SW];   // 16640 B: two ping-pong PADDED row pairs

    Ctx cx;
    cx.t  = threadIdx.x;
    cx.r0 = blockIdx.x * TY;
    const int img = blockIdx.y;
    cx.xin = x + (size_t)img * IMG_H * IMG_W;
    cx.o   = out + (size_t)img * IMG_H * IMG_W;

    // halo assignment: tid 0..7 -> left pad P[tid] = raw col 8-tid;
    //                  tid 8..15 -> right pad P[1024+tid] = raw col 1030-tid
    cx.hasHalo = cx.t < 16;
    cx.hcol    = (cx.t < 8) ? (8 - cx.t) : (1030 - cx.t);
    cx.hoff    = (cx.t < 8) ? cx.t : (1024 + cx.t);

    // 1D taps: k2d = outer(g,g) exactly, g[i] = k2d[i][6]/sqrt(k2d[6][6])
    {
        float c   = k2d[HALF * KS + HALF];
        float inv = 1.0f / sqrtf(c);
        #pragma unroll
        for (int j = 0; j < KS; ++j) cx.g[j] = k2d[j * KS + HALF] * inv;
    }

    // preload rows n=0,1 (input rows r0-6, r0-5, reflected)
    const float* ra = cx.xin + (size_t)reflect_idx(cx.r0 - 6, IMG_H) * IMG_W;
    const float* rb = cx.xin + (size_t)reflect_idx(cx.r0 - 5, IMG_H) * IMG_W;
    float4 cur0 = *reinterpret_cast<const float4*>(ra + 4 * cx.t);
    float4 cur1 = *reinterpret_cast<const float4*>(rb + 4 * cx.t);
    float  hal0 = cx.hasHalo ? ra[cx.hcol] : 0.f;
    float  hal1 = cx.hasHalo ? rb[cx.hcol] : 0.f;

    float4 w[14];
    for (int outer = 0; outer < 4; ++outer) {   // 4*7 = 28 bodies, guard k<22
        body2<0>(outer, cx, s, w, cur0, cur1, hal0, hal1);
        body2<1>(outer, cx, s, w, cur0, cur1, hal0, hal1);
        body2<2>(outer, cx, s, w, cur0, cur1, hal0, hal1);
        body2<3>(outer, cx, s, w, cur0, cur1, hal0, hal1);
        body2<4>(outer, cx, s, w, cur0, cur1, hal0, hal1);
        body2<5>(outer, cx, s, w, cur0, cur1, hal0, hal1);
        body2<6>(outer, cx, s, w, cur0, cur1, hal0, hal1);
    }
}

extern "C" void kernel_launch(void* const* d_in, const int* in_sizes, int n_in,
                              void* d_out, int out_size, void* d_ws, size_t ws_size,
                              hipStream_t stream) {
    const float* x   = (const float*)d_in[0];
    const float* k2d = (const float*)d_in[1];
    float*       out = (float*)d_out;

    dim3 grid(IMG_H / TY, 32);   // 32 strips x 32 images = 1024 blocks
    gauss_blur_stream<<<grid, 256, 0, stream>>>(x, k2d, out);
}

// Round 22
// 55.416 us; speedup vs baseline: 1.1129x; 1.1129x over previous
//
#include <hip/hip_runtime.h>

#define KS    13
#define HALF  6
#define TY    32              // output rows per strip (R13 geometry — best measured)
#define NITER (TY + 12)       // 44 staged rows
#define NK    (NITER / 2)     // 22 iterations, 2 rows per barrier
#define IMG_H 1024
#define IMG_W 1024
#define NSTRIP (IMG_H / TY)   // 32

__device__ __forceinline__ int reflect_idx(int i, int n) {
    if (i < 0) i = -i;
    if (i >= n) i = 2 * n - 2 - i;
    return i;
}

struct Ctx {
    const float* xin;
    float*       o;
    float        g[KS];
    int          t;        // thread's column granule: cols 4t..4t+3
    int          r0;       // strip's first output row
    bool         interior; // 2 <= t <= 253 : LDS window read needs no column reflect
};

// H-filter one staged row from LDS: 20-float window -> 4 outputs.
__device__ __forceinline__ float4 h_filter(const float* srow, const Ctx& cx) {
    float f[20];
    if (cx.interior) {
        #pragma unroll
        for (int k = 0; k < 5; ++k) {
            float4 v = *reinterpret_cast<const float4*>(srow + 4 * cx.t - 8 + 4 * k);
            f[4*k+0] = v.x; f[4*k+1] = v.y; f[4*k+2] = v.z; f[4*k+3] = v.w;
        }
    } else {
        #pragma unroll
        for (int k = 0; k < 20; ++k)
            f[k] = srow[reflect_idx(4 * cx.t - 8 + k, IMG_W)];
    }
    float4 h = make_float4(0.f, 0.f, 0.f, 0.f);
    #pragma unroll
    for (int j = 0; j < KS; ++j) {
        h.x += cx.g[j] * f[2 + j];
        h.y += cx.g[j] * f[3 + j];
        h.z += cx.g[j] * f[4 + j];
        h.w += cx.g[j] * f[5 + j];
    }
    return h;
}

// Iteration k (= outer*7 + U): stages raw rows 2k,2k+1 into the (k&1) LDS pair,
// prefetches rows 2k+2,2k+3 (in flight across barrier+compute, T14), ONE
// barrier, H-filters both into window slots (2U)%14,(2U+1)%14, then (k>=6)
// V-filters -> output rows r0+2k-12, r0+2k-11. Window indices compile-time
// (rule #20). WAR safety: iter k's reads precede barrier_{k+1}; iter k+2's
// rewrites of this pair follow barrier_{k+1} (ping-pong proof).
template<int U>
__device__ __forceinline__ void body2(int outer, const Ctx& cx, float (*s)[IMG_W],
                                      float4 (&w)[14], float4& cur0, float4& cur1)
{
    const int k = outer * 7 + U;
    if (k >= NK) return;                 // block-uniform guard (barrier-safe)
    const int n0 = 2 * k;
    const int bp = (k & 1) * 2;          // LDS buffer pair

    // commit staged rows; then issue next pair's loads
    *reinterpret_cast<float4*>(&s[bp + 0][4 * cx.t]) = cur0;
    *reinterpret_cast<float4*>(&s[bp + 1][4 * cx.t]) = cur1;
    if (k + 1 < NK) {
        const int ra = reflect_idx(cx.r0 + n0 - 4, IMG_H);  // row n0+2
        const int rb = reflect_idx(cx.r0 + n0 - 3, IMG_H);  // row n0+3
        cur0 = *reinterpret_cast<const float4*>(cx.xin + (size_t)ra * IMG_W + 4 * cx.t);
        cur1 = *reinterpret_cast<const float4*>(cx.xin + (size_t)rb * IMG_W + 4 * cx.t);
    }
    __syncthreads();

    // two H-filters into the rolling 14-slot window
    w[(2 * U) % 14]     = h_filter(s[bp + 0], cx);
    w[(2 * U + 1) % 14] = h_filter(s[bp + 1], cx);

    // two V-filters -> output rows r0+n0-12, r0+n0-11
    if (n0 >= 12) {
        float4 a0 = make_float4(0.f, 0.f, 0.f, 0.f);
        float4 a1 = make_float4(0.f, 0.f, 0.f, 0.f);
        #pragma unroll
        for (int j = 0; j < KS; ++j) {
            const float4 v0 = w[(2 * U + 2 + j) % 14];
            const float4 v1 = w[(2 * U + 3 + j) % 14];
            a0.x += cx.g[j] * v0.x;  a1.x += cx.g[j] * v1.x;
            a0.y += cx.g[j] * v0.y;  a1.y += cx.g[j] * v1.y;
            a0.z += cx.g[j] * v0.z;  a1.z += cx.g[j] * v1.z;
            a0.w += cx.g[j] * v0.w;  a1.w += cx.g[j] * v1.w;
        }
        *reinterpret_cast<float4*>(cx.o + (size_t)(cx.r0 + n0 - 12) * IMG_W + 4 * cx.t) = a0;
        *reinterpret_cast<float4*>(cx.o + (size_t)(cx.r0 + n0 - 11) * IMG_W + 4 * cx.t) = a1;
    }
}

// No launch-bounds min-waves (R2: VGPR cap -> spill). ~100 VGPR (R13-identical).
__global__ __launch_bounds__(256) void gauss_blur_stream(
    const float* __restrict__ x, const float* __restrict__ k2d,
    float* __restrict__ out)
{
    __shared__ float s[4][IMG_W];   // 16384 B: two ping-pong row PAIRS

    Ctx cx;
    cx.t  = threadIdx.x;

    // T1 XCD swizzle: wg id = bx + 32*by -> XCD = (bx % 8). Map bx -> strip so
    // each XCD owns 4 vertically-ADJACENT strips per image: their shared 12-row
    // halos then hit that XCD's L2 instead of re-fetching from L3/HBM.
    // strip = 4*(bx%8) + bx/8 is bijective on [0,32) (32 % 8 == 0).
    {
        const int bx = blockIdx.x;
        const int strip = 4 * (bx & 7) + (bx >> 3);
        cx.r0 = strip * TY;
    }
    const int img = blockIdx.y;
    cx.xin = x + (size_t)img * IMG_H * IMG_W;
    cx.o   = out + (size_t)img * IMG_H * IMG_W;
    cx.interior = (cx.t >= 2) && (cx.t <= 253);

    // 1D taps: k2d = outer(g,g) exactly, g[i] = k2d[i][6]/sqrt(k2d[6][6])
    {
        float c   = k2d[HALF * KS + HALF];
        float inv = 1.0f / sqrtf(c);
        #pragma unroll
        for (int j = 0; j < KS; ++j) cx.g[j] = k2d[j * KS + HALF] * inv;
    }

    float4 w[14];
    // preload rows n=0,1 (input rows r0-6, r0-5, reflected)
    float4 cur0 = *reinterpret_cast<const float4*>(
        cx.xin + (size_t)reflect_idx(cx.r0 - 6, IMG_H) * IMG_W + 4 * cx.t);
    float4 cur1 = *reinterpret_cast<const float4*>(
        cx.xin + (size_t)reflect_idx(cx.r0 - 5, IMG_H) * IMG_W + 4 * cx.t);

    for (int outer = 0; outer < 4; ++outer) {   // 4*7 = 28 bodies, guard k<22
        body2<0>(outer, cx, s, w, cur0, cur1);
        body2<1>(outer, cx, s, w, cur0, cur1);
        body2<2>(outer, cx, s, w, cur0, cur1);
        body2<3>(outer, cx, s, w, cur0, cur1);
        body2<4>(outer, cx, s, w, cur0, cur1);
        body2<5>(outer, cx, s, w, cur0, cur1);
        body2<6>(outer, cx, s, w, cur0, cur1);
    }
}

extern "C" void kernel_launch(void* const* d_in, const int* in_sizes, int n_in,
                              void* d_out, int out_size, void* d_ws, size_t ws_size,
                              hipStream_t stream) {
    const float* x   = (const float*)d_in[0];
    const float* k2d = (const float*)d_in[1];
    float*       out = (float*)d_out;

    dim3 grid(NSTRIP, 32);   // 32 strips x 32 images = 1024 blocks
    gauss_blur_stream<<<grid, 256, 0, stream>>>(x, k2d, out);
}

// Round 23
// 53.989 us; speedup vs baseline: 1.1423x; 1.0264x over previous
//
#include <hip/hip_runtime.h>

#define KS    13
#define HALF  6
#define TY    32              // output rows per strip (R13 geometry — best measured)
#define NITER (TY + 12)       // 44 staged rows
#define NK    (NITER / 2)     // 22 iterations, 2 rows per barrier
#define IMG_H 1024
#define IMG_W 1024

__device__ __forceinline__ int reflect_idx(int i, int n) {
    if (i < 0) i = -i;
    if (i >= n) i = 2 * n - 2 - i;
    return i;
}

struct Ctx {
    const float* xin;
    float*       o;
    float        g[KS];
    int          t;        // thread's column granule: cols 4t..4t+3
    int          r0;       // strip's first output row
    bool         interior; // 2 <= t <= 253 : LDS window read needs no column reflect
};

// H-filter one staged row from LDS: 20-float window -> 4 outputs.
__device__ __forceinline__ float4 h_filter(const float* srow, const Ctx& cx) {
    float f[20];
    if (cx.interior) {
        #pragma unroll
        for (int k = 0; k < 5; ++k) {
            float4 v = *reinterpret_cast<const float4*>(srow + 4 * cx.t - 8 + 4 * k);
            f[4*k+0] = v.x; f[4*k+1] = v.y; f[4*k+2] = v.z; f[4*k+3] = v.w;
        }
    } else {
        #pragma unroll
        for (int k = 0; k < 20; ++k)
            f[k] = srow[reflect_idx(4 * cx.t - 8 + k, IMG_W)];
    }
    float4 h = make_float4(0.f, 0.f, 0.f, 0.f);
    #pragma unroll
    for (int j = 0; j < KS; ++j) {
        h.x += cx.g[j] * f[2 + j];
        h.y += cx.g[j] * f[3 + j];
        h.z += cx.g[j] * f[4 + j];
        h.w += cx.g[j] * f[5 + j];
    }
    return h;
}

// Iteration k (= outer*7 + U): stage rows 2k,2k+1 -> (k&1) LDS pair; prefetch
// rows 2k+2,2k+3; barrier; THEN (V-LAG) compute V[k-1] -> output rows
// r0+2k-14, r0+2k-13 from the PRE-H window state (pure register math -- the
// compiler interleaves it with H's independent ds_reads, hiding LDS latency
// that previously had no cover: V[k] depends on H[k], V[k-1] does not); THEN
// H-filter rows 2k,2k+1 into slots (2U)%14,(2U+1)%14 (overwrites rows
// 2k-14,2k-13 AFTER V[k-1] consumed them -- textual order enforces the WAR).
// Window indices compile-time (rule #20); ping-pong WAR proof as R13.
template<int U>
__device__ __forceinline__ void body2(int outer, const Ctx& cx, float (*s)[IMG_W],
                                      float4 (&w)[14], float4& cur0, float4& cur1)
{
    const int k = outer * 7 + U;
    if (k >= NK) return;                 // block-uniform guard (barrier-safe)
    const int n0 = 2 * k;
    const int bp = (k & 1) * 2;          // LDS buffer pair

    // commit staged rows; then issue next pair's loads (T14)
    *reinterpret_cast<float4*>(&s[bp + 0][4 * cx.t]) = cur0;
    *reinterpret_cast<float4*>(&s[bp + 1][4 * cx.t]) = cur1;
    if (k + 1 < NK) {
        const int ra = reflect_idx(cx.r0 + n0 - 4, IMG_H);  // row n0+2
        const int rb = reflect_idx(cx.r0 + n0 - 3, IMG_H);  // row n0+3
        cur0 = *reinterpret_cast<const float4*>(cx.xin + (size_t)ra * IMG_W + 4 * cx.t);
        cur1 = *reinterpret_cast<const float4*>(cx.xin + (size_t)rb * IMG_W + 4 * cx.t);
    }
    __syncthreads();

    // V[k-1] (lagged): output rows r0+n0-14, r0+n0-13; row m -> slot m%14, so
    // a0 taps slots (2U+j)%14, a1 taps (2U+1+j)%14 (j=0..12), all pre-H values.
    if (n0 >= 14) {
        float4 a0 = make_float4(0.f, 0.f, 0.f, 0.f);
        float4 a1 = make_float4(0.f, 0.f, 0.f, 0.f);
        #pragma unroll
        for (int j = 0; j < KS; ++j) {
            const float4 v0 = w[(2 * U + j) % 14];
            const float4 v1 = w[(2 * U + 1 + j) % 14];
            a0.x += cx.g[j] * v0.x;  a1.x += cx.g[j] * v1.x;
            a0.y += cx.g[j] * v0.y;  a1.y += cx.g[j] * v1.y;
            a0.z += cx.g[j] * v0.z;  a1.z += cx.g[j] * v1.z;
            a0.w += cx.g[j] * v0.w;  a1.w += cx.g[j] * v1.w;
        }
        *reinterpret_cast<float4*>(cx.o + (size_t)(cx.r0 + n0 - 14) * IMG_W + 4 * cx.t) = a0;
        *reinterpret_cast<float4*>(cx.o + (size_t)(cx.r0 + n0 - 13) * IMG_W + 4 * cx.t) = a1;
    }

    // H[k]: ds_reads are independent of the V math above -> scheduler overlaps
    w[(2 * U) % 14]     = h_filter(s[bp + 0], cx);
    w[(2 * U + 1) % 14] = h_filter(s[bp + 1], cx);
}

// No launch-bounds min-waves (R2: VGPR cap -> spill). Expect ~105 VGPR.
__global__ __launch_bounds__(256) void gauss_blur_stream(
    const float* __restrict__ x, const float* __restrict__ k2d,
    float* __restrict__ out)
{
    __shared__ float s[4][IMG_W];   // 16384 B: two ping-pong row PAIRS

    Ctx cx;
    cx.t  = threadIdx.x;
    cx.r0 = blockIdx.x * TY;
    const int img = blockIdx.y;
    cx.xin = x + (size_t)img * IMG_H * IMG_W;
    cx.o   = out + (size_t)img * IMG_H * IMG_W;
    cx.interior = (cx.t >= 2) && (cx.t <= 253);

    // 1D taps: k2d = outer(g,g) exactly, g[i] = k2d[i][6]/sqrt(k2d[6][6])
    {
        float c   = k2d[HALF * KS + HALF];
        float inv = 1.0f / sqrtf(c);
        #pragma unroll
        for (int j = 0; j < KS; ++j) cx.g[j] = k2d[j * KS + HALF] * inv;
    }

    float4 w[14];
    // preload rows n=0,1 (input rows r0-6, r0-5, reflected)
    float4 cur0 = *reinterpret_cast<const float4*>(
        cx.xin + (size_t)reflect_idx(cx.r0 - 6, IMG_H) * IMG_W + 4 * cx.t);
    float4 cur1 = *reinterpret_cast<const float4*>(
        cx.xin + (size_t)reflect_idx(cx.r0 - 5, IMG_H) * IMG_W + 4 * cx.t);

    for (int outer = 0; outer < 4; ++outer) {   // 4*7 = 28 bodies, guard k<22
        body2<0>(outer, cx, s, w, cur0, cur1);
        body2<1>(outer, cx, s, w, cur0, cur1);
        body2<2>(outer, cx, s, w, cur0, cur1);
        body2<3>(outer, cx, s, w, cur0, cur1);
        body2<4>(outer, cx, s, w, cur0, cur1);
        body2<5>(outer, cx, s, w, cur0, cur1);
        body2<6>(outer, cx, s, w, cur0, cur1);
    }

    // epilogue: V[21] -> output rows r0+30, r0+31. After iter k=21 the window
    // holds rows 30..43; row m -> slot m%14: a0 taps (2+j)%14, a1 taps (3+j)%14.
    {
        float4 a0 = make_float4(0.f, 0.f, 0.f, 0.f);
        float4 a1 = make_float4(0.f, 0.f, 0.f, 0.f);
        #pragma unroll
        for (int j = 0; j < KS; ++j) {
            const float4 v0 = w[(2 + j) % 14];
            const float4 v1 = w[(3 + j) % 14];
            a0.x += cx.g[j] * v0.x;  a1.x += cx.g[j] * v1.x;
            a0.y += cx.g[j] * v0.y;  a1.y += cx.g[j] * v1.y;
            a0.z += cx.g[j] * v0.z;  a1.z += cx.g[j] * v1.z;
            a0.w += cx.g[j] * v0.w;  a1.w += cx.g[j] * v1.w;
        }
        *reinterpret_cast<float4*>(cx.o + (size_t)(cx.r0 + 30) * IMG_W + 4 * cx.t) = a0;
        *reinterpret_cast<float4*>(cx.o + (size_t)(cx.r0 + 31) * IMG_W + 4 * cx.t) = a1;
    }
}

extern "C" void kernel_launch(void* const* d_in, const int* in_sizes, int n_in,
                              void* d_out, int out_size, void* d_ws, size_t ws_size,
                              hipStream_t stream) {
    const float* x   = (const float*)d_in[0];
    const float* k2d = (const float*)d_in[1];
    float*       out = (float*)d_out;

    dim3 grid(IMG_H / TY, 32);   // 32 strips x 32 images = 1024 blocks
    gauss_blur_stream<<<grid, 256, 0, stream>>>(x, k2d, out);
}

// Round 24
// 51.866 us; speedup vs baseline: 1.1891x; 1.0409x over previous
//
#include <hip/hip_runtime.h>

#define KS    13
#define HALF  6
#define TY    64              // output rows per strip: halo amp 1.19 vs 1.375 @32
#define NITER (TY + 12)       // 76 staged rows
#define NK    (NITER / 2)     // 38 iterations, 2 rows per barrier
#define IMG_H 1024
#define IMG_W 1024

__device__ __forceinline__ int reflect_idx(int i, int n) {
    if (i < 0) i = -i;
    if (i >= n) i = 2 * n - 2 - i;
    return i;
}

struct Ctx {
    const float* xin;
    float*       o;
    float        g[KS];
    int          t;        // thread's column granule: cols 4t..4t+3
    int          r0;       // strip's first output row
    bool         interior; // 2 <= t <= 253 : LDS window read needs no column reflect
};

// H-filter one staged row from LDS: 20-float window -> 4 outputs.
__device__ __forceinline__ float4 h_filter(const float* srow, const Ctx& cx) {
    float f[20];
    if (cx.interior) {
        #pragma unroll
        for (int k = 0; k < 5; ++k) {
            float4 v = *reinterpret_cast<const float4*>(srow + 4 * cx.t - 8 + 4 * k);
            f[4*k+0] = v.x; f[4*k+1] = v.y; f[4*k+2] = v.z; f[4*k+3] = v.w;
        }
    } else {
        #pragma unroll
        for (int k = 0; k < 20; ++k)
            f[k] = srow[reflect_idx(4 * cx.t - 8 + k, IMG_W)];
    }
    float4 h = make_float4(0.f, 0.f, 0.f, 0.f);
    #pragma unroll
    for (int j = 0; j < KS; ++j) {
        h.x += cx.g[j] * f[2 + j];
        h.y += cx.g[j] * f[3 + j];
        h.z += cx.g[j] * f[4 + j];
        h.w += cx.g[j] * f[5 + j];
    }
    return h;
}

// Iteration k (= outer*7 + U, U == k mod 7): stage rows 2k,2k+1 -> (k&1) LDS
// pair; prefetch rows 2k+2,2k+3 (T14); barrier; V[k-1] (lagged, pure register
// math overlapping H's ds_reads) -> output rows r0+2k-14, r0+2k-13; then H[k]
// into slots (2U)%14,(2U+1)%14 (row m lives at slot m%14; 2k%14 == 2U).
// Window indices compile-time (rule #20); ping-pong WAR proof as R13.
template<int U>
__device__ __forceinline__ void body2(int outer, const Ctx& cx, float (*s)[IMG_W],
                                      float4 (&w)[14], float4& cur0, float4& cur1)
{
    const int k = outer * 7 + U;
    if (k >= NK) return;                 // block-uniform guard (barrier-safe)
    const int n0 = 2 * k;
    const int bp = (k & 1) * 2;          // LDS buffer pair

    // commit staged rows; then issue next pair's loads (T14)
    *reinterpret_cast<float4*>(&s[bp + 0][4 * cx.t]) = cur0;
    *reinterpret_cast<float4*>(&s[bp + 1][4 * cx.t]) = cur1;
    if (k + 1 < NK) {
        const int ra = reflect_idx(cx.r0 + n0 - 4, IMG_H);  // row n0+2
        const int rb = reflect_idx(cx.r0 + n0 - 3, IMG_H);  // row n0+3
        cur0 = *reinterpret_cast<const float4*>(cx.xin + (size_t)ra * IMG_W + 4 * cx.t);
        cur1 = *reinterpret_cast<const float4*>(cx.xin + (size_t)rb * IMG_W + 4 * cx.t);
    }
    __syncthreads();

    // V[k-1] (lagged): output rows r0+n0-14, r0+n0-13; taps slots (2U+j)%14,
    // (2U+1+j)%14 -- all pre-H window values.
    if (n0 >= 14) {
        float4 a0 = make_float4(0.f, 0.f, 0.f, 0.f);
        float4 a1 = make_float4(0.f, 0.f, 0.f, 0.f);
        #pragma unroll
        for (int j = 0; j < KS; ++j) {
            const float4 v0 = w[(2 * U + j) % 14];
            const float4 v1 = w[(2 * U + 1 + j) % 14];
            a0.x += cx.g[j] * v0.x;  a1.x += cx.g[j] * v1.x;
            a0.y += cx.g[j] * v0.y;  a1.y += cx.g[j] * v1.y;
            a0.z += cx.g[j] * v0.z;  a1.z += cx.g[j] * v1.z;
            a0.w += cx.g[j] * v0.w;  a1.w += cx.g[j] * v1.w;
        }
        *reinterpret_cast<float4*>(cx.o + (size_t)(cx.r0 + n0 - 14) * IMG_W + 4 * cx.t) = a0;
        *reinterpret_cast<float4*>(cx.o + (size_t)(cx.r0 + n0 - 13) * IMG_W + 4 * cx.t) = a1;
    }

    // H[k]: ds_reads are independent of the V math above -> scheduler overlaps
    w[(2 * U) % 14]     = h_filter(s[bp + 0], cx);
    w[(2 * U + 1) % 14] = h_filter(s[bp + 1], cx);
}

// No launch-bounds min-waves (R2: VGPR cap -> spill). Expect ~92 VGPR.
__global__ __launch_bounds__(256) void gauss_blur_stream(
    const float* __restrict__ x, const float* __restrict__ k2d,
    float* __restrict__ out)
{
    __shared__ float s[4][IMG_W];   // 16384 B: two ping-pong row PAIRS

    Ctx cx;
    cx.t  = threadIdx.x;
    cx.r0 = blockIdx.x * TY;
    const int img = blockIdx.y;
    cx.xin = x + (size_t)img * IMG_H * IMG_W;
    cx.o   = out + (size_t)img * IMG_H * IMG_W;
    cx.interior = (cx.t >= 2) && (cx.t <= 253);

    // 1D taps: k2d = outer(g,g) exactly, g[i] = k2d[i][6]/sqrt(k2d[6][6])
    {
        float c   = k2d[HALF * KS + HALF];
        float inv = 1.0f / sqrtf(c);
        #pragma unroll
        for (int j = 0; j < KS; ++j) cx.g[j] = k2d[j * KS + HALF] * inv;
    }

    float4 w[14];
    // preload rows n=0,1 (input rows r0-6, r0-5, reflected)
    float4 cur0 = *reinterpret_cast<const float4*>(
        cx.xin + (size_t)reflect_idx(cx.r0 - 6, IMG_H) * IMG_W + 4 * cx.t);
    float4 cur1 = *reinterpret_cast<const float4*>(
        cx.xin + (size_t)reflect_idx(cx.r0 - 5, IMG_H) * IMG_W + 4 * cx.t);

    for (int outer = 0; outer < 6; ++outer) {   // 6*7 = 42 bodies, guard k<38
        body2<0>(outer, cx, s, w, cur0, cur1);
        body2<1>(outer, cx, s, w, cur0, cur1);
        body2<2>(outer, cx, s, w, cur0, cur1);
        body2<3>(outer, cx, s, w, cur0, cur1);
        body2<4>(outer, cx, s, w, cur0, cur1);
        body2<5>(outer, cx, s, w, cur0, cur1);
        body2<6>(outer, cx, s, w, cur0, cur1);
    }

    // epilogue: V[37] -> output rows r0+62, r0+63. As-if k'=38 (38 mod 7 = 3):
    // taps slots (6+j)%14, (7+j)%14.
    {
        float4 a0 = make_float4(0.f, 0.f, 0.f, 0.f);
        float4 a1 = make_float4(0.f, 0.f, 0.f, 0.f);
        #pragma unroll
        for (int j = 0; j < KS; ++j) {
            const float4 v0 = w[(6 + j) % 14];
            const float4 v1 = w[(7 + j) % 14];
            a0.x += cx.g[j] * v0.x;  a1.x += cx.g[j] * v1.x;
            a0.y += cx.g[j] * v0.y;  a1.y += cx.g[j] * v1.y;
            a0.z += cx.g[j] * v0.z;  a1.z += cx.g[j] * v1.z;
            a0.w += cx.g[j] * v0.w;  a1.w += cx.g[j] * v1.w;
        }
        *reinterpret_cast<float4*>(cx.o + (size_t)(cx.r0 + 62) * IMG_W + 4 * cx.t) = a0;
        *reinterpret_cast<float4*>(cx.o + (size_t)(cx.r0 + 63) * IMG_W + 4 * cx.t) = a1;
    }
}

extern "C" void kernel_launch(void* const* d_in, const int* in_sizes, int n_in,
                              void* d_out, int out_size, void* d_ws, size_t ws_size,
                              hipStream_t stream) {
    const float* x   = (const float*)d_in[0];
    const float* k2d = (const float*)d_in[1];
    float*       out = (float*)d_out;

    dim3 grid(IMG_H / TY, 32);   // 16 strips x 32 images = 512 blocks
    gauss_blur_stream<<<grid, 256, 0, stream>>>(x, k2d, out);
}